// Round 5
// baseline (152.397 us; speedup 1.0000x reference)
//
#include <hip/hip_runtime.h>
#include <float.h>

#define NPTS   8192
#define NB     4
#define BLK    256

typedef __attribute__((ext_vector_type(8))) short          short8;
typedef __attribute__((ext_vector_type(8))) unsigned short ushort8;
typedef __attribute__((ext_vector_type(4))) float          f32x4;

__device__ inline unsigned short f2bf(float x) {           // RNE f32 -> bf16 bits
  unsigned u = __builtin_bit_cast(unsigned, x);
  u = u + 0x7FFFu + ((u >> 16) & 1u);
  return (unsigned short)(u >> 16);
}
__device__ inline float bf2f(unsigned short h) {
  unsigned u = ((unsigned)h) << 16;
  return __builtin_bit_cast(float, u);
}

// Pack each point into K=16 bf16 slots (14 used).
// A row: [hx,hy,hz, lx,ly,lz, hx,hy,hz, lx,ly,lz, 1,1, 0,0]
// B row: [-2hx,-2hy,-2hz, -2hx,-2hy,-2hz, -2lx,-2ly,-2lz, -2lx,-2ly,-2lz, s2h,s2l, 0,0]
// => sum_k A[q][k]*B[s][k] = -2*(q . s) + |s|^2   (exact to ~2^-18 per coord)
__global__ __launch_bounds__(BLK) void prep_kernel(
    const float* __restrict__ tpl, const float* __restrict__ src,
    unsigned short* __restrict__ apack, unsigned short* __restrict__ bpack) {
  int p = blockIdx.x * BLK + threadIdx.x;   // 0..65535 = cloud*8192 + i
  int cloud = p >> 13;                      // b*2 + (0=tpl,1=src)
  int i = p & (NPTS - 1);
  int b = cloud >> 1;
  const float* base = ((cloud & 1) ? src : tpl) + ((size_t)b * NPTS + i) * 3;
  float x = base[0], y = base[1], z = base[2];
  unsigned short hx = f2bf(x), hy = f2bf(y), hz = f2bf(z);
  float fx = bf2f(hx), fy = bf2f(hy), fz = bf2f(hz);
  unsigned short lx = f2bf(x - fx), ly = f2bf(y - fy), lz = f2bf(z - fz);
  float s2 = fmaf(x, x, fmaf(y, y, z * z));
  unsigned short s2h = f2bf(s2);
  unsigned short s2l = f2bf(s2 - bf2f(s2h));
  unsigned short nhx = f2bf(-2.0f * fx), nhy = f2bf(-2.0f * fy), nhz = f2bf(-2.0f * fz);
  unsigned short nlx = f2bf(-2.0f * bf2f(lx)), nly = f2bf(-2.0f * bf2f(ly)),
                 nlz = f2bf(-2.0f * bf2f(lz));
  const unsigned short ONE = 0x3F80;

  ushort8 a0 = {hx, hy, hz, lx, ly, lz, hx, hy};
  ushort8 a1 = {hz, lx, ly, lz, ONE, ONE, 0, 0};
  ushort8 b0 = {nhx, nhy, nhz, nhx, nhy, nhz, nlx, nly};
  ushort8 b1 = {nlz, nlx, nly, nlz, s2h, s2l, 0, 0};
  *(ushort8*)(apack + (size_t)p * 16)     = a0;
  *(ushort8*)(apack + (size_t)p * 16 + 8) = a1;
  *(ushort8*)(bpack + (size_t)p * 16)     = b0;
  *(ushort8*)(bpack + (size_t)p * 16 + 8) = b1;
}

// Main: 512 blocks. bd = blockIdx&7 (one bd per XCD -> B-pack stays in its L2).
// Block = 4 waves x 2 query tiles (128 queries); each wave sweeps all 512
// source tiles: 1 B-frag global load + 2 mfma + 8 fminf per tile.
// Fragment maps (16x16x32 bf16, per verified example):
//   A: lane l holds A[row=l&15][k=8*(l>>4)+j]; B: B[k=8*(l>>4)+j][col=l&15]
//   D: lane l reg j = D[row=(l>>4)*4+j][col=l&15]
__global__ __launch_bounds__(BLK) void chamfer_mfma_kernel(
    const float* __restrict__ tpl, const float* __restrict__ src,
    const unsigned short* __restrict__ apack,
    const unsigned short* __restrict__ bpack,
    float* __restrict__ partial) {
  __shared__ float red[16];
  const int bd   = blockIdx.x & 7;
  const int qblk = blockIdx.x >> 3;
  const int b = bd >> 1, dir = bd & 1;
  const int t = threadIdx.x, w = t >> 6, l = t & 63;
  const int acloud = bd;        // queries: dir0->tpl(b*2), dir1->src(b*2+1)
  const int bcloud = bd ^ 1;    // sources: the other cloud
  const int qbase = qblk * 128 + w * 32;

  // A fragments for 2 query tiles; lanes 32-63 feed k=16..31 -> zero.
  short8 a0 = {0, 0, 0, 0, 0, 0, 0, 0};
  short8 a1 = a0;
  if (l < 32) {
    const unsigned short* ab =
        apack + ((size_t)acloud * NPTS + qbase + (l & 15)) * 16 + (l >> 4) * 8;
    a0 = *(const short8*)ab;
    a1 = *(const short8*)(ab + 16 * 16);
  }

  // B-frag pointer; lanes 32-63 duplicate lanes 0-31 (their products hit A=0).
  const unsigned short* bb =
      bpack + (size_t)bcloud * NPTS * 16 + ((l & 15) * 16 + ((l >> 4) & 1) * 8);

  f32x4 m0 = {FLT_MAX, FLT_MAX, FLT_MAX, FLT_MAX};
  f32x4 m1 = m0;
  const f32x4 zero = {0.f, 0.f, 0.f, 0.f};

  #pragma unroll 8
  for (int st = 0; st < NPTS / 16; ++st) {
    short8 bf = *(const short8*)(bb + (size_t)st * 256);
    f32x4 d0 = __builtin_amdgcn_mfma_f32_16x16x32_bf16(a0, bf, zero, 0, 0, 0);
    f32x4 d1 = __builtin_amdgcn_mfma_f32_16x16x32_bf16(a1, bf, zero, 0, 0, 0);
    m0[0] = fminf(m0[0], d0[0]); m0[1] = fminf(m0[1], d0[1]);
    m0[2] = fminf(m0[2], d0[2]); m0[3] = fminf(m0[3], d0[3]);
    m1[0] = fminf(m1[0], d1[0]); m1[1] = fminf(m1[1], d1[1]);
    m1[2] = fminf(m1[2], d1[2]); m1[3] = fminf(m1[3], d1[3]);
  }

  // Cross-lane min over the 16 column-lanes (xor 1,2,4,8 stays in-group).
  #pragma unroll
  for (int off = 1; off <= 8; off <<= 1) {
    m0[0] = fminf(m0[0], __shfl_xor(m0[0], off, 64));
    m0[1] = fminf(m0[1], __shfl_xor(m0[1], off, 64));
    m0[2] = fminf(m0[2], __shfl_xor(m0[2], off, 64));
    m0[3] = fminf(m0[3], __shfl_xor(m0[3], off, 64));
    m1[0] = fminf(m1[0], __shfl_xor(m1[0], off, 64));
    m1[1] = fminf(m1[1], __shfl_xor(m1[1], off, 64));
    m1[2] = fminf(m1[2], __shfl_xor(m1[2], off, 64));
    m1[3] = fminf(m1[3], __shfl_xor(m1[3], off, 64));
  }

  // Lane c==0 of each 16-lane group owns rows (l>>4)*4 + j; add |q|^2, sum.
  float lsum = 0.0f;
  if ((l & 15) == 0) {
    const float* qp = ((dir == 0) ? tpl : src) + (size_t)b * NPTS * 3;
    int rg = (l >> 4) * 4;
    #pragma unroll
    for (int j = 0; j < 4; ++j) {
      {
        const float* q = qp + (size_t)(qbase + rg + j) * 3;
        lsum += m0[j] + fmaf(q[0], q[0], fmaf(q[1], q[1], q[2] * q[2]));
      }
      {
        const float* q = qp + (size_t)(qbase + 16 + rg + j) * 3;
        lsum += m1[j] + fmaf(q[0], q[0], fmaf(q[1], q[1], q[2] * q[2]));
      }
    }
    red[w * 4 + (l >> 4)] = lsum;
  }
  __syncthreads();
  if (t == 0) {
    float s = 0.0f;
    #pragma unroll
    for (int i = 0; i < 16; ++i) s += red[i];
    partial[blockIdx.x] = s;
  }
}

// Final: fixed-order sum of 512 partials; mean over 2*B*N = 32768 mins.
__global__ __launch_bounds__(BLK) void final512_kernel(
    const float* __restrict__ partial, float* __restrict__ out) {
  __shared__ float wsum[BLK / 64];
  int t = threadIdx.x;
  float v = partial[t] + partial[t + 256];
  #pragma unroll
  for (int off = 32; off > 0; off >>= 1) v += __shfl_down(v, off, 64);
  if ((t & 63) == 0) wsum[t >> 6] = v;
  __syncthreads();
  if (t == 0)
    out[0] = (wsum[0] + wsum[1] + wsum[2] + wsum[3]) * (1.0f / 32768.0f);
}

// ---------------- fallback (R2-style) if ws is too small --------------------
#define TILE   2048
#define NTILES (NPTS / TILE)
#define QBLKS  (NPTS / BLK)

__global__ __launch_bounds__(BLK) void chamfer_min_kernel(
    const float* __restrict__ tpl, const float* __restrict__ src,
    float* __restrict__ partial) {
  __shared__ float4 s4[TILE];
  __shared__ float wsum[BLK / 64];
  const int b = blockIdx.z, dir = blockIdx.y;
  const float* qb = (dir == 0 ? tpl : src) + (size_t)b * NPTS * 3;
  const float* rb = (dir == 0 ? src : tpl) + (size_t)b * NPTS * 3;
  const int t = threadIdx.x;
  const int q = blockIdx.x * BLK + t;
  const float qx = qb[3 * q + 0], qy = qb[3 * q + 1], qz = qb[3 * q + 2];
  const float q2 = fmaf(qx, qx, fmaf(qy, qy, qz * qz));
  float b0 = FLT_MAX, b1 = FLT_MAX;
  for (int tile = 0; tile < NTILES; ++tile) {
    const float* rt = rb + 3 * TILE * tile;
    #pragma unroll
    for (int k = 0; k < TILE / BLK; ++k) {
      int p = t + BLK * k;
      float x = rt[3 * p + 0], y = rt[3 * p + 1], z = rt[3 * p + 2];
      s4[p] = make_float4(-2.0f * x, -2.0f * y, -2.0f * z,
                          fmaf(x, x, fmaf(y, y, z * z)));
    }
    __syncthreads();
    #pragma unroll 2
    for (int m = 0; m < TILE; m += 2) {
      float4 p0 = s4[m + 0], p1 = s4[m + 1];
      float d0 = fmaf(qx, p0.x, fmaf(qy, p0.y, fmaf(qz, p0.z, p0.w)));
      float d1 = fmaf(qx, p1.x, fmaf(qy, p1.y, fmaf(qz, p1.z, p1.w)));
      b0 = fminf(b0, fminf(d0, d1));
      b1 = fminf(b1, d0);
    }
    __syncthreads();
  }
  float best = fminf(b0, b1) + q2;
  float v = best;
  #pragma unroll
  for (int off = 32; off > 0; off >>= 1) v += __shfl_down(v, off, 64);
  if ((t & 63) == 0) wsum[t >> 6] = v;
  __syncthreads();
  if (t == 0)
    partial[((b * 2 + dir) * QBLKS) + blockIdx.x] =
        wsum[0] + wsum[1] + wsum[2] + wsum[3];
}

__global__ __launch_bounds__(BLK) void final256_kernel(
    const float* __restrict__ partial, float* __restrict__ out) {
  __shared__ float wsum[BLK / 64];
  int t = threadIdx.x;
  float v = partial[t];
  #pragma unroll
  for (int off = 32; off > 0; off >>= 1) v += __shfl_down(v, off, 64);
  if ((t & 63) == 0) wsum[t >> 6] = v;
  __syncthreads();
  if (t == 0)
    out[0] = (wsum[0] + wsum[1] + wsum[2] + wsum[3]) * (1.0f / 32768.0f);
}

// ----------------------------------------------------------------------------
extern "C" void kernel_launch(void* const* d_in, const int* in_sizes, int n_in,
                              void* d_out, int out_size, void* d_ws, size_t ws_size,
                              hipStream_t stream) {
  const float* tpl = (const float*)d_in[0];   // template (4, 8192, 3) f32
  const float* src = (const float*)d_in[1];   // source   (4, 8192, 3) f32
  float* out = (float*)d_out;

  const size_t pack_elems = (size_t)NB * 2 * NPTS * 16;    // 1 M ushorts each
  const size_t need = pack_elems * 2 * sizeof(unsigned short) + 512 * sizeof(float);

  if (ws_size >= need) {
    unsigned short* apack = (unsigned short*)d_ws;
    unsigned short* bpack = apack + pack_elems;
    float* partial = (float*)(bpack + pack_elems);
    prep_kernel<<<(NB * 2 * NPTS) / BLK, BLK, 0, stream>>>(tpl, src, apack, bpack);
    chamfer_mfma_kernel<<<512, BLK, 0, stream>>>(tpl, src, apack, bpack, partial);
    final512_kernel<<<1, BLK, 0, stream>>>(partial, out);
  } else {
    float* partial = (float*)d_ws;            // 256 floats
    dim3 grid(QBLKS, 2, NB);
    chamfer_min_kernel<<<grid, BLK, 0, stream>>>(tpl, src, partial);
    final256_kernel<<<1, BLK, 0, stream>>>(partial, out);
  }
}

// Round 6
// 43.376 us; speedup vs baseline: 3.5134x; 3.5134x over previous
//
#include <hip/hip_runtime.h>
#include <float.h>

#define NPTS   8192
#define NB     4
#define BLK    256
#define NBDIR  (NB * 2)             // 8 (batch, direction) pairs
#define SSPLIT 4                    // source splits per bd
#define SRCPB  (NPTS / SSPLIT)      // 2048 sources per block
#define STAGE  1024                 // source points per LDS stage (32 KB)
#define NSTAGE (SRCPB / STAGE)      // 2
#define QPW    64                   // queries per wave (2 MFMA tiles of 32)
#define QPB    (4 * QPW)            // 256 queries per block
#define NQB    (NPTS / QPB)         // 32 query blocks per bd

typedef __attribute__((ext_vector_type(8)))  short          short8;
typedef __attribute__((ext_vector_type(8)))  unsigned short ushort8;
typedef __attribute__((ext_vector_type(16))) float          f32x16;

__device__ inline unsigned short f2bf(float x) {           // RNE f32 -> bf16
  unsigned u = __builtin_bit_cast(unsigned, x);
  u = u + 0x7FFFu + ((u >> 16) & 1u);
  return (unsigned short)(u >> 16);
}
__device__ inline float bf2f(unsigned short h) {
  unsigned u = ((unsigned)h) << 16;
  return __builtin_bit_cast(float, u);
}

// Pack per point, K=16 split over two 8-slot halves:
//   A row (same for both halves):  [hx,hy,hz,lx,ly,lz,1,0]
//   B lo half: [-2hx,-2hy,-2hz,-2hx,-2hy,-2hz,s2h,0]
//   B hi half: [-2lx,-2ly,-2lz,-2lx,-2ly,-2lz,s2l,0]
// sum_k A[q][k]*B[s][k] = -2*(q.s) + |s|^2 (each term exact bf16 product, f32 acc).
// A halves identical => result invariant to lane-half<->k-half assignment.
__global__ __launch_bounds__(BLK) void prep_kernel(
    const float* __restrict__ tpl, const float* __restrict__ src,
    ushort8* __restrict__ apack8, ushort8* __restrict__ bpack8) {
  int p = blockIdx.x * BLK + threadIdx.x;   // 0..65535 = cloud*8192 + i
  int cloud = p >> 13;                      // b*2 + (0=tpl,1=src)
  int i = p & (NPTS - 1);
  int b = cloud >> 1;
  const float* base = ((cloud & 1) ? src : tpl) + ((size_t)b * NPTS + i) * 3;
  float x = base[0], y = base[1], z = base[2];
  unsigned short hx = f2bf(x), hy = f2bf(y), hz = f2bf(z);
  float fx = bf2f(hx), fy = bf2f(hy), fz = bf2f(hz);
  unsigned short lx = f2bf(x - fx), ly = f2bf(y - fy), lz = f2bf(z - fz);
  float s2 = fmaf(x, x, fmaf(y, y, z * z));
  unsigned short s2h = f2bf(s2);
  unsigned short s2l = f2bf(s2 - bf2f(s2h));
  // -2 * bf16 value is exact in bf16 (exponent bump + sign).
  unsigned short nhx = f2bf(-2.0f * fx), nhy = f2bf(-2.0f * fy), nhz = f2bf(-2.0f * fz);
  unsigned short nlx = f2bf(-2.0f * bf2f(lx)), nly = f2bf(-2.0f * bf2f(ly)),
                 nlz = f2bf(-2.0f * bf2f(lz));
  const unsigned short ONE = 0x3F80;

  ushort8 arow = {hx, hy, hz, lx, ly, lz, ONE, 0};
  ushort8 blo  = {nhx, nhy, nhz, nhx, nhy, nhz, s2h, 0};
  ushort8 bhi  = {nlx, nly, nlz, nlx, nly, nlz, s2l, 0};
  apack8[p] = arow;                                      // [cloud][point]
  bpack8[((size_t)cloud * 2 + 0) * NPTS + i] = blo;      // [cloud][half][point]
  bpack8[((size_t)cloud * 2 + 1) * NPTS + i] = bhi;
}

// Main: 1024 blocks (4/CU). Block = (bd, ssplit, qblk): 256 queries x 2048
// sources. B staged in LDS as [half][1024 pts][16B] -> stride-16 contiguous
// ds_read_b128, conflict-free. Per source tile: 2 x mfma_32x32x16 + 32 fmin.
// Fragment maps: A row=l&31, B col=l&31 (k-half via l>>5, order-invariant);
// C/D (verified m74/m101): col=l&31, row=(reg&3)+8*(reg>>2)+4*(l>>5).
__global__ __launch_bounds__(BLK) void chamfer_mfma32_kernel(
    const ushort8* __restrict__ apack8, const ushort8* __restrict__ bpack8,
    float* __restrict__ cand) {
  __shared__ ushort8 blds8[2 * STAGE];    // 32 KB
  const int bd   = blockIdx.x & 7;        // one bd per XCD slot
  const int rest = blockIdx.x >> 3;
  const int ss   = rest & (SSPLIT - 1);
  const int qblk = rest >> 2;
  const int t = threadIdx.x, w = t >> 6, l = t & 63;
  const int acloud = bd, bcloud = bd ^ 1;
  const int qbase = qblk * QPB + w * QPW;

  // A fragments for 2 query tiles (8 bf16 each; same for both lane halves).
  short8 a0 = __builtin_bit_cast(short8, apack8[(size_t)acloud * NPTS + qbase + (l & 31)]);
  short8 a1 = __builtin_bit_cast(short8, apack8[(size_t)acloud * NPTS + qbase + 32 + (l & 31)]);

  f32x16 m0, m1;
  #pragma unroll
  for (int j = 0; j < 16; ++j) { m0[j] = FLT_MAX; m1[j] = FLT_MAX; }
  const f32x16 zero = {0.f, 0.f, 0.f, 0.f, 0.f, 0.f, 0.f, 0.f,
                       0.f, 0.f, 0.f, 0.f, 0.f, 0.f, 0.f, 0.f};

  const size_t bbase = (size_t)bcloud * 2 * NPTS + (size_t)ss * SRCPB;

  for (int sg = 0; sg < NSTAGE; ++sg) {
    if (sg) __syncthreads();
    #pragma unroll
    for (int i = 0; i < STAGE / BLK; ++i) {   // 4 x (2 x 16B) per thread
      int c = t + BLK * i;
      blds8[c]         = bpack8[bbase + sg * STAGE + c];          // lo plane
      blds8[STAGE + c] = bpack8[bbase + NPTS + sg * STAGE + c];   // hi plane
    }
    __syncthreads();

    const int rb = (l >> 5) * STAGE + (l & 31);
    #pragma unroll 4
    for (int st = 0; st < STAGE / 32; ++st) {
      short8 bf = __builtin_bit_cast(short8, blds8[rb + st * 32]);
      f32x16 d0 = __builtin_amdgcn_mfma_f32_32x32x16_bf16(a0, bf, zero, 0, 0, 0);
      #pragma unroll
      for (int j = 0; j < 16; ++j) m0[j] = fminf(m0[j], d0[j]);
      f32x16 d1 = __builtin_amdgcn_mfma_f32_32x32x16_bf16(a1, bf, zero, 0, 0, 0);
      #pragma unroll
      for (int j = 0; j < 16; ++j) m1[j] = fminf(m1[j], d1[j]);
    }
  }

  // Min over the 32 source-columns (lanes within each 32-lane group).
  #pragma unroll
  for (int off = 1; off <= 16; off <<= 1) {
    #pragma unroll
    for (int j = 0; j < 16; ++j) {
      m0[j] = fminf(m0[j], __shfl_xor(m0[j], off, 64));
      m1[j] = fminf(m1[j], __shfl_xor(m1[j], off, 64));
    }
  }

  // Lanes 0 and 32 own 16 query-rows each; write per-query partial mins.
  if ((l & 31) == 0) {
    const int radd = (l >> 5) * 4;
    float* cq = cand + ((size_t)(bd * SSPLIT + ss) * NPTS) + qbase;
    #pragma unroll
    for (int r = 0; r < 16; ++r) {
      int row = (r & 3) + 8 * (r >> 2) + radd;
      cq[row]      = m0[r];
      cq[32 + row] = m1[r];
    }
  }
}

// Combine: per query, min over SSPLIT partials + |q|^2, block-sum.
__global__ __launch_bounds__(BLK) void combine_kernel(
    const float* __restrict__ tpl, const float* __restrict__ src,
    const float* __restrict__ cand, float* __restrict__ partial) {
  __shared__ float wsum[BLK / 64];
  const int qblk = blockIdx.x & (NQB - 1);
  const int bd   = blockIdx.x >> 5;
  const int b = bd >> 1, dir = bd & 1;
  const int t = threadIdx.x;
  const int q = qblk * BLK + t;
  const float* base = cand + (size_t)bd * SSPLIT * NPTS + q;
  float v = fminf(fminf(base[0], base[NPTS]),
                  fminf(base[2 * NPTS], base[3 * NPTS]));
  const float* qp = (dir ? src : tpl) + ((size_t)b * NPTS + q) * 3;
  v += fmaf(qp[0], qp[0], fmaf(qp[1], qp[1], qp[2] * qp[2]));
  #pragma unroll
  for (int off = 32; off > 0; off >>= 1) v += __shfl_down(v, off, 64);
  if ((t & 63) == 0) wsum[t >> 6] = v;
  __syncthreads();
  if (t == 0)
    partial[blockIdx.x] = wsum[0] + wsum[1] + wsum[2] + wsum[3];
}

// Final: fixed-order sum of 256 partials; mean over 2*B*N = 32768 mins.
__global__ __launch_bounds__(BLK) void final256_kernel(
    const float* __restrict__ partial, float* __restrict__ out) {
  __shared__ float wsum[BLK / 64];
  int t = threadIdx.x;
  float v = partial[t];
  #pragma unroll
  for (int off = 32; off > 0; off >>= 1) v += __shfl_down(v, off, 64);
  if ((t & 63) == 0) wsum[t >> 6] = v;
  __syncthreads();
  if (t == 0)
    out[0] = (wsum[0] + wsum[1] + wsum[2] + wsum[3]) * (1.0f / 32768.0f);
}

// ---------------- fallback (R2-style) if ws is too small --------------------
#define TILE   2048
#define NTILES (NPTS / TILE)
#define QBLKS  (NPTS / BLK)

__global__ __launch_bounds__(BLK) void chamfer_min_kernel(
    const float* __restrict__ tpl, const float* __restrict__ src,
    float* __restrict__ partial) {
  __shared__ float4 s4[TILE];
  __shared__ float wsum[BLK / 64];
  const int b = blockIdx.z, dir = blockIdx.y;
  const float* qb = (dir == 0 ? tpl : src) + (size_t)b * NPTS * 3;
  const float* rb = (dir == 0 ? src : tpl) + (size_t)b * NPTS * 3;
  const int t = threadIdx.x;
  const int q = blockIdx.x * BLK + t;
  const float qx = qb[3 * q + 0], qy = qb[3 * q + 1], qz = qb[3 * q + 2];
  const float q2 = fmaf(qx, qx, fmaf(qy, qy, qz * qz));
  float b0 = FLT_MAX, b1 = FLT_MAX;
  for (int tile = 0; tile < NTILES; ++tile) {
    const float* rt = rb + 3 * TILE * tile;
    #pragma unroll
    for (int k = 0; k < TILE / BLK; ++k) {
      int p = t + BLK * k;
      float x = rt[3 * p + 0], y = rt[3 * p + 1], z = rt[3 * p + 2];
      s4[p] = make_float4(-2.0f * x, -2.0f * y, -2.0f * z,
                          fmaf(x, x, fmaf(y, y, z * z)));
    }
    __syncthreads();
    #pragma unroll 2
    for (int m = 0; m < TILE; m += 2) {
      float4 p0 = s4[m + 0], p1 = s4[m + 1];
      float d0 = fmaf(qx, p0.x, fmaf(qy, p0.y, fmaf(qz, p0.z, p0.w)));
      float d1 = fmaf(qx, p1.x, fmaf(qy, p1.y, fmaf(qz, p1.z, p1.w)));
      b0 = fminf(b0, fminf(d0, d1));
      b1 = fminf(b1, d0);
    }
    __syncthreads();
  }
  float best = fminf(b0, b1) + q2;
  float v = best;
  #pragma unroll
  for (int off = 32; off > 0; off >>= 1) v += __shfl_down(v, off, 64);
  if ((t & 63) == 0) wsum[t >> 6] = v;
  __syncthreads();
  if (t == 0)
    partial[((b * 2 + dir) * QBLKS) + blockIdx.x] =
        wsum[0] + wsum[1] + wsum[2] + wsum[3];
}

// ----------------------------------------------------------------------------
extern "C" void kernel_launch(void* const* d_in, const int* in_sizes, int n_in,
                              void* d_out, int out_size, void* d_ws, size_t ws_size,
                              hipStream_t stream) {
  const float* tpl = (const float*)d_in[0];   // template (4, 8192, 3) f32
  const float* src = (const float*)d_in[1];   // source   (4, 8192, 3) f32
  float* out = (float*)d_out;

  const size_t a_chunks = (size_t)NBDIR * NPTS;          // 64 K ushort8 (1 MB)
  const size_t b_chunks = (size_t)NBDIR * 2 * NPTS;      // 128 K ushort8 (2 MB)
  const size_t cand_elems = (size_t)NBDIR * SSPLIT * NPTS; // 256 K f32 (1 MB)
  const size_t need = (a_chunks + b_chunks) * 16 +
                      (cand_elems + NBDIR * NQB) * sizeof(float);

  if (ws_size >= need) {
    ushort8* apack8 = (ushort8*)d_ws;
    ushort8* bpack8 = apack8 + a_chunks;
    float*   cand   = (float*)(bpack8 + b_chunks);
    float*   partial = cand + cand_elems;
    prep_kernel<<<(NBDIR * NPTS) / BLK, BLK, 0, stream>>>(tpl, src, apack8, bpack8);
    chamfer_mfma32_kernel<<<NBDIR * SSPLIT * NQB, BLK, 0, stream>>>(apack8, bpack8, cand);
    combine_kernel<<<NBDIR * NQB, BLK, 0, stream>>>(tpl, src, cand, partial);
    final256_kernel<<<1, BLK, 0, stream>>>(partial, out);
  } else {
    float* partial = (float*)d_ws;            // 256 floats
    dim3 grid(QBLKS, 2, NB);
    chamfer_min_kernel<<<grid, BLK, 0, stream>>>(tpl, src, partial);
    final256_kernel<<<1, BLK, 0, stream>>>(partial, out);
  }
}